// Round 1
// baseline (183.166 us; speedup 1.0000x reference)
//
#include <hip/hip_runtime.h>
#include <hip/hip_bf16.h>

#define EPSF 1e-5f

typedef __attribute__((ext_vector_type(8))) short bf16x8;
typedef __attribute__((ext_vector_type(4))) float f32x4;
typedef __attribute__((ext_vector_type(2))) unsigned int u32x2;
typedef __attribute__((ext_vector_type(4))) unsigned int u32x4;
typedef __attribute__((ext_vector_type(4))) int i32x4;

constexpr int B_ = 2, N_ = 16384;
constexpr int HSTR = 72;   // hbuf row stride (bf16 elems)
constexpr int RSTR = 72;
constexpr int PPW  = 4;    // points per wave
constexpr int PPB  = 16;   // points per block
constexpr size_t PP_BYTES = (size_t)B_ * N_ * 16;   // 512 KiB padded points

__device__ __forceinline__ short f2bf(float f) {
    __hip_bfloat16 h = __float2bfloat16(f);
    short s; __builtin_memcpy(&s, &h, 2); return s;
}
// packed f32x2 -> bf16x2 (v_cvt_pk_bf16_f32)
__device__ __forceinline__ unsigned int pkbf(float a, float b) {
    float2 f2; f2.x = a; f2.y = b;
    __hip_bfloat162 h = __float22bfloat162_rn(f2);
    unsigned int u; __builtin_memcpy(&u, &h, 4); return u;
}

// prep: points -> padded float4 (one dwordx4 gather instead of 3 divergent dwords)
__global__ __launch_bounds__(256) void prep_points(
    const float* __restrict__ pts, float* __restrict__ pp)
{
    const int i = blockIdx.x * 256 + threadIdx.x;
    if (i < B_ * N_) {
        f32x4 o = { pts[3 * i], pts[3 * i + 1], pts[3 * i + 2], 0.f };
        ((f32x4*)pp)[i] = o;
    }
}

// bridgenet7 changes vs bridgenet6:
//  - neighbor indices for the feature gather loaded directly as int4
//    (gidx[pt*32 + mt*16 + quad*4 + r] == old __shfl(giv[mt], quad*4+r)),
//    killing 8 ds_bpermute per point and the gidx->shfl->gather chain
//  - index loads prefetched one point ahead (gidx lines are cold: touched once)
//  - XCD batch-affinity swizzle: XCDs 0-3 own batch 0, 4-7 own batch 1 so the
//    per-XCD gather working set (4 MiB features) fits the 4 MiB L2
//  - weight staging split across all 4 waves, vectorized f32x4 loads
//  - wb3 (out-proj B-frags) moved from LDS to phase-D registers: LDS
//    37376 -> 28928 B => 5 blocks/CU when VGPR <= 102
template<bool PAD>
__global__ __launch_bounds__(256) void bridgenet7(
    const float* __restrict__ points,     // raw (PAD=false)
    const float* __restrict__ pp,         // padded float4 (PAD=true)
    const float* __restrict__ features,
    const int*   __restrict__ gidx,
    const float* __restrict__ Wpos,
    const float* __restrict__ bposv,
    const float* __restrict__ bn1g, const float* __restrict__ bn1b,
    const float* __restrict__ bn1m, const float* __restrict__ bn1v,
    const float* __restrict__ Wgcm,
    const float* __restrict__ bgcm,
    const float* __restrict__ bn2g, const float* __restrict__ bn2b,
    const float* __restrict__ bn2m, const float* __restrict__ bn2v,
    const float* __restrict__ Watt,
    const float* __restrict__ batt,
    const float* __restrict__ Wout,
    const float* __restrict__ bout,
    const float* __restrict__ lng, const float* __restrict__ lnb,
    float* __restrict__ out)
{
    __shared__ __align__(16) short hbuf[4][32 * HSTR];
    __shared__ __align__(16) short resstage[PPB * RSTR];
    __shared__ __align__(16) short wb2[8 * 64 * 8];   // GCM B-frags: (nt*2+ks, lane, 8)

    const int t    = threadIdx.x;
    const int w    = t >> 6;
    const int l    = t & 63;
    const int l15  = l & 15;
    const int quad = l >> 4;
    const int c4   = l15 * 4;

    // ---- XCD batch-affinity swizzle (round-robin wg%8 -> XCD assumed) ----
    // bijective: blk = (xcd>=4)*1024 + (wg/8)*4 + (xcd&3)
    const int wg  = blockIdx.x;
    const int blk = ((wg & 7) >> 2) * 1024 + (wg >> 3) * 4 + (wg & 3);

    // ---- cooperative weight staging: 8 (nt,ks) frag-sets, 2 per wave ----
    {
        #pragma unroll
        for (int u = 0; u < 2; ++u) {
            const int s  = w * 2 + u;
            const int nt = s >> 1, ks = s & 1;
            const float* g = Wgcm + (c4 + nt) * 64 + ks * 32 + quad * 8;
            const f32x4 w0 = *(const f32x4*)g;
            const f32x4 w1 = *(const f32x4*)(g + 4);
            bf16x8 f2;
            #pragma unroll
            for (int j = 0; j < 4; ++j) {
                f2[j]     = f2bf(w0[j]);
                f2[j + 4] = f2bf(w1[j]);
            }
            *(bf16x8*)&wb2[(s * 64 + l) * 8] = f2;
        }
    }

    // ---- per-wave constant state (kept lean) ----
    bf16x8 bposf[4];
    #pragma unroll
    for (int nt = 0; nt < 4; ++nt) {
        const int c = c4 + nt;
        #pragma unroll
        for (int j = 0; j < 8; ++j) {
            const int g = quad * 8 + j;
            bposf[nt][j] = f2bf(g < 10 ? Wpos[c * 10 + g] : 0.f);
        }
    }
    f32x4 ps1, pb1, ps2, pb2;
    {
        const f32x4 g1 = *(const f32x4*)(bn1g + c4);
        const f32x4 b1 = *(const f32x4*)(bn1b + c4);
        const f32x4 m1 = *(const f32x4*)(bn1m + c4);
        const f32x4 v1 = *(const f32x4*)(bn1v + c4);
        const f32x4 bp = *(const f32x4*)(bposv + c4);
        const f32x4 g2 = *(const f32x4*)(bn2g + c4);
        const f32x4 b2 = *(const f32x4*)(bn2b + c4);
        const f32x4 m2 = *(const f32x4*)(bn2m + c4);
        const f32x4 v2 = *(const f32x4*)(bn2v + c4);
        const f32x4 bg = *(const f32x4*)(bgcm + c4);
        #pragma unroll
        for (int j = 0; j < 4; ++j) {
            ps1[j] = g1[j] * rsqrtf(v1[j] + EPSF);
            pb1[j] = ps1[j] * (bp[j] - m1[j]) + b1[j];
            ps2[j] = g2[j] * rsqrtf(v2[j] + EPSF);
            pb2[j] = ps2[j] * (bg[j] - m2[j]) + b2[j];
        }
    }
    float wat[2][4];
    #pragma unroll
    for (int mt = 0; mt < 2; ++mt)
        #pragma unroll
        for (int r = 0; r < 4; ++r)
            wat[mt][r] = Watt[mt * 16 + quad * 4 + r];
    const float battv = batt[0];

    const f32x4 zero4 = {0.f, 0.f, 0.f, 0.f};
    short* hb = hbuf[w];
    const int base = blk * PPB + w * PPW;
    const int bb   = (blk >> 10) * N_;

    // ---- prefetch iteration-0 indices (before the barrier: free overlap) ----
    i32x4 gi4[2];
    int   giv[2];
    gi4[0] = *(const i32x4*)(gidx + (size_t)base * 32 + quad * 4);
    gi4[1] = *(const i32x4*)(gidx + (size_t)base * 32 + 16 + quad * 4);
    giv[0] = gidx[(size_t)base * 32 + l15];
    giv[1] = gidx[(size_t)base * 32 + 16 + l15];

    __syncthreads();   // weight LDS ready

    for (int i = 0; i < PPW; ++i) {
        const int pt = base + i;

        // --- feature gathers: indices already resident, issue immediately ---
        f32x4 f4[2][4];
        #pragma unroll
        for (int mt = 0; mt < 2; ++mt)
            #pragma unroll
            for (int r = 0; r < 4; ++r)
                f4[mt][r] = *(const f32x4*)(features + (size_t)(bb + gi4[mt][r]) * 64 + c4);

        const f32x4 resid = *(const f32x4*)(features + (size_t)pt * 64 + c4);
        float xi0, xi1, xi2;
        float px[2], py[2], pz[2];
        if (PAD) {
            const f32x4 x4 = *(const f32x4*)(pp + (size_t)pt * 4);
            xi0 = x4[0]; xi1 = x4[1]; xi2 = x4[2];
            #pragma unroll
            for (int mt = 0; mt < 2; ++mt) {
                const f32x4 p4 = *(const f32x4*)(pp + (size_t)(bb + giv[mt]) * 4);
                px[mt] = p4[0]; py[mt] = p4[1]; pz[mt] = p4[2];
            }
        } else {
            xi0 = points[(size_t)pt * 3];
            xi1 = points[(size_t)pt * 3 + 1];
            xi2 = points[(size_t)pt * 3 + 2];
            #pragma unroll
            for (int mt = 0; mt < 2; ++mt) {
                const float* ppt = points + (size_t)(bb + giv[mt]) * 3;
                px[mt] = ppt[0]; py[mt] = ppt[1]; pz[mt] = ppt[2];
            }
        }

        // --- prefetch next iteration's indices (gidx lines are always cold) ---
        const int ptn = base + (i + 1 < PPW ? i + 1 : i);
        i32x4 ngi[2];
        int   ngiv[2];
        ngi[0]  = *(const i32x4*)(gidx + (size_t)ptn * 32 + quad * 4);
        ngi[1]  = *(const i32x4*)(gidx + (size_t)ptn * 32 + 16 + quad * 4);
        ngiv[0] = gidx[(size_t)ptn * 32 + l15];
        ngiv[1] = gidx[(size_t)ptn * 32 + 16 + l15];

        // --- geo A-frags via packed bf16 converts ---
        bf16x8 ageo[2];
        #pragma unroll
        for (int mt = 0; mt < 2; ++mt) {
            const float dx = xi0 - px[mt], dy = xi1 - py[mt], dz = xi2 - pz[mt];
            const float dist = sqrtf(dx * dx + dy * dy + dz * dz);
            u32x4 u = {0u, 0u, 0u, 0u};
            if (quad == 0) {
                u[0] = pkbf(xi0, xi1); u[1] = pkbf(xi2, px[mt]);
                u[2] = pkbf(py[mt], pz[mt]); u[3] = pkbf(dx, dy);
            } else if (quad == 1) {
                u[0] = pkbf(dz, dist);
            }
            __builtin_memcpy(&ageo[mt], &u, 16);
        }

        // --- pos-MLP MFMA ---
        f32x4 acc1[2][4];
        #pragma unroll
        for (int mt = 0; mt < 2; ++mt)
            #pragma unroll
            for (int nt = 0; nt < 4; ++nt)
                acc1[mt][nt] = __builtin_amdgcn_mfma_f32_16x16x32_bf16(
                    ageo[mt], bposf[nt], zero4, 0, 0, 0);

        // --- epilogue 1: bn1+relu + feature add, packed converts, b64 writes ---
        #pragma unroll
        for (int mt = 0; mt < 2; ++mt)
            #pragma unroll
            for (int r = 0; r < 4; ++r) {
                const int k = mt * 16 + quad * 4 + r;
                float v[4];
                #pragma unroll
                for (int j = 0; j < 4; ++j)
                    v[j] = f4[mt][r][j] + fmaxf(ps1[j] * acc1[mt][j][r] + pb1[j], 0.f);
                u32x2 hv = { pkbf(v[0], v[1]), pkbf(v[2], v[3]) };
                *(u32x2*)&hb[k * HSTR + c4] = hv;
            }

        // --- GCM: A-frags from LDS, B-frags from LDS, 16 MFMAs ---
        bf16x8 a2[2][2];
        #pragma unroll
        for (int mt = 0; mt < 2; ++mt)
            #pragma unroll
            for (int ks = 0; ks < 2; ++ks)
                a2[mt][ks] = *(const bf16x8*)&hb[(mt * 16 + l15) * HSTR + ks * 32 + quad * 8];
        f32x4 acc2[2][4];
        #pragma unroll
        for (int nt = 0; nt < 4; ++nt) {
            const bf16x8 b0 = *(const bf16x8*)&wb2[((nt * 2 + 0) * 64 + l) * 8];
            const bf16x8 b1 = *(const bf16x8*)&wb2[((nt * 2 + 1) * 64 + l) * 8];
            #pragma unroll
            for (int mt = 0; mt < 2; ++mt) {
                f32x4 a = __builtin_amdgcn_mfma_f32_16x16x32_bf16(a2[mt][0], b0, zero4, 0, 0, 0);
                acc2[mt][nt] = __builtin_amdgcn_mfma_f32_16x16x32_bf16(a2[mt][1], b1, a, 0, 0, 0);
            }
        }

        // --- epilogue 2: bn2+relu, attention softmax (shift-invariant), pool ---
        float res[4];
        {
            float sp[4], mk[4];
            #pragma unroll
            for (int nt = 0; nt < 4; ++nt) {
                sp[nt] = 0.f; mk[nt] = 0.f;
                #pragma unroll
                for (int mt = 0; mt < 2; ++mt)
                    #pragma unroll
                    for (int r = 0; r < 4; ++r) {
                        const float h2 = fmaxf(ps2[nt] * acc2[mt][nt][r] + pb2[nt], 0.f);
                        sp[nt] += h2 * wat[mt][r];
                        mk[nt] = fmaxf(mk[nt], h2);
                    }
                sp[nt] += __shfl_xor(sp[nt], 16);
                sp[nt] += __shfl_xor(sp[nt], 32);
                mk[nt] = fmaxf(mk[nt], __shfl_xor(mk[nt], 16));
                mk[nt] = fmaxf(mk[nt], __shfl_xor(mk[nt], 32));
            }
            float e[4], s = 0.f;
            #pragma unroll
            for (int nt = 0; nt < 4; ++nt) { e[nt] = __expf(sp[nt] + battv); s += e[nt]; }
            #pragma unroll
            for (int o = 1; o < 16; o <<= 1) s += __shfl_xor(s, o);
            const float inv = 1.f / s;
            #pragma unroll
            for (int nt = 0; nt < 4; ++nt)
                res[nt] = e[nt] * inv * mk[nt] + resid[nt];
        }
        if (quad == 0) {
            u32x2 rv = { pkbf(res[0], res[1]), pkbf(res[2], res[3]) };
            *(u32x2*)&resstage[(w * PPW + i) * RSTR + c4] = rv;
        }

        // rotate prefetched indices
        gi4[0] = ngi[0]; gi4[1] = ngi[1];
        giv[0] = ngiv[0]; giv[1] = ngiv[1];
    }

    __syncthreads();

    // ---------- phase D: batched out-matmul + LayerNorm + relu ----------
    const f32x4 lngv  = *(const f32x4*)(lng + c4);
    const f32x4 lnbv  = *(const f32x4*)(lnb + c4);
    const f32x4 boutv = *(const f32x4*)(bout + c4);
    bf16x8 a3[2];
    #pragma unroll
    for (int ks = 0; ks < 2; ++ks)
        a3[ks] = *(const bf16x8*)&resstage[l15 * RSTR + ks * 32 + quad * 8];
    f32x4 acc3[4];
    #pragma unroll
    for (int nt = 0; nt < 4; ++nt) {
        // out-proj B-frags straight from L2-resident Wout (was LDS wb3)
        const float* g = Wout + (c4 + nt) * 64 + quad * 8;
        const f32x4 w00 = *(const f32x4*)g;
        const f32x4 w01 = *(const f32x4*)(g + 4);
        const f32x4 w10 = *(const f32x4*)(g + 32);
        const f32x4 w11 = *(const f32x4*)(g + 36);
        bf16x8 b0, b1;
        #pragma unroll
        for (int j = 0; j < 4; ++j) {
            b0[j]     = f2bf(w00[j]);
            b0[j + 4] = f2bf(w01[j]);
            b1[j]     = f2bf(w10[j]);
            b1[j + 4] = f2bf(w11[j]);
        }
        f32x4 a = __builtin_amdgcn_mfma_f32_16x16x32_bf16(a3[0], b0, zero4, 0, 0, 0);
        acc3[nt] = __builtin_amdgcn_mfma_f32_16x16x32_bf16(a3[1], b1, a, 0, 0, 0);
    }
    float y[4], s = 0.f;
    #pragma unroll
    for (int nt = 0; nt < 4; ++nt) { y[nt] = acc3[nt][w] + boutv[nt]; s += y[nt]; }
    #pragma unroll
    for (int o = 1; o < 16; o <<= 1) s += __shfl_xor(s, o);
    const float mu = s * (1.f / 64.f);
    float dv[4], v2 = 0.f;
    #pragma unroll
    for (int nt = 0; nt < 4; ++nt) { dv[nt] = y[nt] - mu; v2 += dv[nt] * dv[nt]; }
    #pragma unroll
    for (int o = 1; o < 16; o <<= 1) v2 += __shfl_xor(v2, o);
    const float rs = rsqrtf(v2 * (1.f / 64.f) + EPSF);
    const int pto = blk * PPB + quad * 4 + w;   // swizzle-corrected output index
    f32x4 ov;
    #pragma unroll
    for (int nt = 0; nt < 4; ++nt)
        ov[nt] = fmaxf(lngv[nt] * dv[nt] * rs + lnbv[nt], 0.f);
    *(f32x4*)(out + (size_t)pto * 64 + c4) = ov;
}

extern "C" void kernel_launch(void* const* d_in, const int* in_sizes, int n_in,
                              void* d_out, int out_size, void* d_ws, size_t ws_size,
                              hipStream_t stream) {
    const float* points   = (const float*)d_in[0];
    const float* features = (const float*)d_in[1];
    const int*   gidxp    = (const int*)d_in[2];
    const bool   pad      = (ws_size >= PP_BYTES);
    float* pp = (float*)d_ws;
    if (pad) {
        hipLaunchKernelGGL(prep_points, dim3((B_ * N_ + 255) / 256), dim3(256), 0, stream,
                           points, pp);
        hipLaunchKernelGGL((bridgenet7<true>), dim3((B_ * N_) / PPB), dim3(256), 0, stream,
            points, pp, features, gidxp,
            (const float*)d_in[3],  (const float*)d_in[4],
            (const float*)d_in[5],  (const float*)d_in[6],  (const float*)d_in[7],  (const float*)d_in[8],
            (const float*)d_in[9],  (const float*)d_in[10],
            (const float*)d_in[11], (const float*)d_in[12], (const float*)d_in[13], (const float*)d_in[14],
            (const float*)d_in[15], (const float*)d_in[16],
            (const float*)d_in[17], (const float*)d_in[18],
            (const float*)d_in[19], (const float*)d_in[20],
            (float*)d_out);
    } else {
        hipLaunchKernelGGL((bridgenet7<false>), dim3((B_ * N_) / PPB), dim3(256), 0, stream,
            points, pp, features, gidxp,
            (const float*)d_in[3],  (const float*)d_in[4],
            (const float*)d_in[5],  (const float*)d_in[6],  (const float*)d_in[7],  (const float*)d_in[8],
            (const float*)d_in[9],  (const float*)d_in[10],
            (const float*)d_in[11], (const float*)d_in[12], (const float*)d_in[13], (const float*)d_in[14],
            (const float*)d_in[15], (const float*)d_in[16],
            (const float*)d_in[17], (const float*)d_in[18],
            (const float*)d_in[19], (const float*)d_in[20],
            (float*)d_out);
    }
}

// Round 2
// 180.637 us; speedup vs baseline: 1.0140x; 1.0140x over previous
//
#include <hip/hip_runtime.h>
#include <hip/hip_bf16.h>

#define EPSF 1e-5f

typedef __attribute__((ext_vector_type(8))) short bf16x8;
typedef __attribute__((ext_vector_type(4))) float f32x4;
typedef __attribute__((ext_vector_type(2))) unsigned int u32x2;
typedef __attribute__((ext_vector_type(4))) unsigned int u32x4;
typedef __attribute__((ext_vector_type(4))) int i32x4;

constexpr int B_ = 2, N_ = 16384;
constexpr int HSTR = 72;   // hbuf row stride (bf16 elems)
constexpr int RSTR = 72;
constexpr int PPW  = 4;    // points per wave
constexpr int PPB  = 16;   // points per block
constexpr size_t PP_BYTES = (size_t)B_ * N_ * 16;   // 512 KiB padded points

__device__ __forceinline__ short f2bf(float f) {
    __hip_bfloat16 h = __float2bfloat16(f);
    short s; __builtin_memcpy(&s, &h, 2); return s;
}
// packed f32x2 -> bf16x2 (v_cvt_pk_bf16_f32)
__device__ __forceinline__ unsigned int pkbf(float a, float b) {
    float2 f2; f2.x = a; f2.y = b;
    __hip_bfloat162 h = __float22bfloat162_rn(f2);
    unsigned int u; __builtin_memcpy(&u, &h, 4); return u;
}

// prep: points -> padded float4 (one dwordx4 gather instead of 3 divergent dwords)
__global__ __launch_bounds__(256) void prep_points(
    const float* __restrict__ pts, float* __restrict__ pp)
{
    const int i = blockIdx.x * 256 + threadIdx.x;
    if (i < B_ * N_) {
        f32x4 o = { pts[3 * i], pts[3 * i + 1], pts[3 * i + 2], 0.f };
        ((f32x4*)pp)[i] = o;
    }
}

// bridgenet8 vs bridgenet7 (post-mortem driven):
//  - EXPLICIT 2-DEEP POINT PIPELINE: LOADD(i+1) (feature gathers + point
//    loads + geo->ageo pack) issues before COMPUTE(i); LOADI(i+2) keeps the
//    index->gather chain off the critical path. Gather latency (the dominant
//    ~500cy/point exposed stall at 1.6 waves/SIMD residency) now hides under
//    the ~1500cy of register/LDS-local compute of the previous point.
//  - phase-D wb3 back in LDS (R1's register-conversion tail lengthened every
//    block's lifetime); wb2+wb3 staged cooperatively by all 4 waves.
//  - kept from R1: int4 direct index loads (no ds_bpermute), XCD
//    batch-affinity swizzle (FETCH 44->33 MB, verified).
template<bool PAD>
__global__ __launch_bounds__(256) void bridgenet8(
    const float* __restrict__ points,     // raw (PAD=false)
    const float* __restrict__ pp,         // padded float4 (PAD=true)
    const float* __restrict__ features,
    const int*   __restrict__ gidx,
    const float* __restrict__ Wpos,
    const float* __restrict__ bposv,
    const float* __restrict__ bn1g, const float* __restrict__ bn1b,
    const float* __restrict__ bn1m, const float* __restrict__ bn1v,
    const float* __restrict__ Wgcm,
    const float* __restrict__ bgcm,
    const float* __restrict__ bn2g, const float* __restrict__ bn2b,
    const float* __restrict__ bn2m, const float* __restrict__ bn2v,
    const float* __restrict__ Watt,
    const float* __restrict__ batt,
    const float* __restrict__ Wout,
    const float* __restrict__ bout,
    const float* __restrict__ lng, const float* __restrict__ lnb,
    float* __restrict__ out)
{
    __shared__ __align__(16) short hbuf[4][32 * HSTR];
    __shared__ __align__(16) short resstage[PPB * RSTR];
    __shared__ __align__(16) short wb2[8 * 64 * 8];   // GCM B-frags: (nt*2+ks, lane, 8)
    __shared__ __align__(16) short wb3[8 * 64 * 8];   // out B-frags

    const int t    = threadIdx.x;
    const int w    = t >> 6;
    const int l    = t & 63;
    const int l15  = l & 15;
    const int quad = l >> 4;
    const int c4   = l15 * 4;

    // ---- XCD batch-affinity swizzle (round-robin wg%8 -> XCD) ----
    const int wg  = blockIdx.x;
    const int blk = ((wg & 7) >> 2) * 1024 + (wg >> 3) * 4 + (wg & 3);

    // ---- cooperative weight staging: 16 frag-sets (8 wb2, 8 wb3), 4/wave ----
    {
        #pragma unroll
        for (int u = 0; u < 4; ++u) {
            const int s  = w * 4 + u;          // 0..15
            const int nt = (s >> 1) & 3, ks = s & 1;
            const float* src = (s < 8 ? Wgcm : Wout) + (c4 + nt) * 64 + ks * 32 + quad * 8;
            const f32x4 w0 = *(const f32x4*)src;
            const f32x4 w1 = *(const f32x4*)(src + 4);
            bf16x8 f;
            #pragma unroll
            for (int j = 0; j < 4; ++j) {
                f[j]     = f2bf(w0[j]);
                f[j + 4] = f2bf(w1[j]);
            }
            short* dst = (s < 8 ? wb2 : wb3);
            *(bf16x8*)&dst[((s & 7) * 64 + l) * 8] = f;
        }
    }

    // ---- per-wave constant state ----
    bf16x8 bposf[4];
    #pragma unroll
    for (int nt = 0; nt < 4; ++nt) {
        const int c = c4 + nt;
        #pragma unroll
        for (int j = 0; j < 8; ++j) {
            const int g = quad * 8 + j;
            bposf[nt][j] = f2bf(g < 10 ? Wpos[c * 10 + g] : 0.f);
        }
    }
    f32x4 ps1, pb1, ps2, pb2;
    {
        const f32x4 g1 = *(const f32x4*)(bn1g + c4);
        const f32x4 b1 = *(const f32x4*)(bn1b + c4);
        const f32x4 m1 = *(const f32x4*)(bn1m + c4);
        const f32x4 v1 = *(const f32x4*)(bn1v + c4);
        const f32x4 bp = *(const f32x4*)(bposv + c4);
        const f32x4 g2 = *(const f32x4*)(bn2g + c4);
        const f32x4 b2 = *(const f32x4*)(bn2b + c4);
        const f32x4 m2 = *(const f32x4*)(bn2m + c4);
        const f32x4 v2 = *(const f32x4*)(bn2v + c4);
        const f32x4 bg = *(const f32x4*)(bgcm + c4);
        #pragma unroll
        for (int j = 0; j < 4; ++j) {
            ps1[j] = g1[j] * rsqrtf(v1[j] + EPSF);
            pb1[j] = ps1[j] * (bp[j] - m1[j]) + b1[j];
            ps2[j] = g2[j] * rsqrtf(v2[j] + EPSF);
            pb2[j] = ps2[j] * (bg[j] - m2[j]) + b2[j];
        }
    }
    float wat[2][4];
    #pragma unroll
    for (int mt = 0; mt < 2; ++mt)
        #pragma unroll
        for (int r = 0; r < 4; ++r)
            wat[mt][r] = Watt[mt * 16 + quad * 4 + r];
    const float battv = batt[0];

    const f32x4 zero4 = {0.f, 0.f, 0.f, 0.f};
    short* hb = hbuf[w];
    const int base = blk * PPB + w * PPW;
    const int bb   = (blk >> 10) * N_;

    // ---- pipeline helpers ----
    auto LOADI = [&](int pt, i32x4 (&gi)[2]) {
        gi[0] = *(const i32x4*)(gidx + (size_t)pt * 32 + quad * 4);
        gi[1] = *(const i32x4*)(gidx + (size_t)pt * 32 + 16 + quad * 4);
    };
    // loads everything point pt needs before epilogue-2, and packs geo A-frags
    auto LOADD = [&](int pt, const i32x4 (&gi)[2],
                     f32x4 (&f4)[2][4], bf16x8 (&ageo)[2]) {
        #pragma unroll
        for (int mt = 0; mt < 2; ++mt)
            #pragma unroll
            for (int r = 0; r < 4; ++r)
                f4[mt][r] = *(const f32x4*)(features + (size_t)(bb + gi[mt][r]) * 64 + c4);
        int gv[2];
        gv[0] = gidx[(size_t)pt * 32 + l15];
        gv[1] = gidx[(size_t)pt * 32 + 16 + l15];
        float xi0, xi1, xi2, px[2], py[2], pz[2];
        if (PAD) {
            const f32x4 x4 = *(const f32x4*)(pp + (size_t)pt * 4);
            xi0 = x4[0]; xi1 = x4[1]; xi2 = x4[2];
            #pragma unroll
            for (int mt = 0; mt < 2; ++mt) {
                const f32x4 p4 = *(const f32x4*)(pp + (size_t)(bb + gv[mt]) * 4);
                px[mt] = p4[0]; py[mt] = p4[1]; pz[mt] = p4[2];
            }
        } else {
            xi0 = points[(size_t)pt * 3];
            xi1 = points[(size_t)pt * 3 + 1];
            xi2 = points[(size_t)pt * 3 + 2];
            #pragma unroll
            for (int mt = 0; mt < 2; ++mt) {
                const float* ppt = points + (size_t)(bb + gv[mt]) * 3;
                px[mt] = ppt[0]; py[mt] = ppt[1]; pz[mt] = ppt[2];
            }
        }
        #pragma unroll
        for (int mt = 0; mt < 2; ++mt) {
            const float dx = xi0 - px[mt], dy = xi1 - py[mt], dz = xi2 - pz[mt];
            const float dist = sqrtf(dx * dx + dy * dy + dz * dz);
            u32x4 u = {0u, 0u, 0u, 0u};
            if (quad == 0) {
                u[0] = pkbf(xi0, xi1); u[1] = pkbf(xi2, px[mt]);
                u[2] = pkbf(py[mt], pz[mt]); u[3] = pkbf(dx, dy);
            } else if (quad == 1) {
                u[0] = pkbf(dz, dist);
            }
            __builtin_memcpy(&ageo[mt], &u, 16);
        }
    };

    // ---- prologue: fill pipeline for points base+0 / base+1 ----
    i32x4 giC[2], giN[2];
    LOADI(base, giC);
    LOADI(base + 1, giN);
    f32x4  f4c[2][4];
    bf16x8 ageoc[2];
    LOADD(base, giC, f4c, ageoc);

    __syncthreads();   // weight LDS ready

    #pragma unroll
    for (int i = 0; i < PPW; ++i) {
        const int pt = base + i;

        // --- pipeline stage: next point's data, next-next point's indices ---
        f32x4  f4n[2][4];
        bf16x8 ageon[2];
        i32x4  giN2[2];
        if (i + 1 < PPW) LOADD(pt + 1, giN, f4n, ageon);
        if (i + 2 < PPW) LOADI(pt + 2, giN2);

        // resid for the CURRENT point: issued here, consumed in epilogue 2
        const f32x4 resid = *(const f32x4*)(features + (size_t)pt * 64 + c4);

        // --- pos-MLP MFMA (inputs already in registers) ---
        f32x4 acc1[2][4];
        #pragma unroll
        for (int mt = 0; mt < 2; ++mt)
            #pragma unroll
            for (int nt = 0; nt < 4; ++nt)
                acc1[mt][nt] = __builtin_amdgcn_mfma_f32_16x16x32_bf16(
                    ageoc[mt], bposf[nt], zero4, 0, 0, 0);

        // --- epilogue 1: bn1+relu + feature add, packed converts, b64 writes ---
        #pragma unroll
        for (int mt = 0; mt < 2; ++mt)
            #pragma unroll
            for (int r = 0; r < 4; ++r) {
                const int k = mt * 16 + quad * 4 + r;
                float v[4];
                #pragma unroll
                for (int j = 0; j < 4; ++j)
                    v[j] = f4c[mt][r][j] + fmaxf(ps1[j] * acc1[mt][j][r] + pb1[j], 0.f);
                u32x2 hv = { pkbf(v[0], v[1]), pkbf(v[2], v[3]) };
                *(u32x2*)&hb[k * HSTR + c4] = hv;
            }

        // --- GCM: A-frags from LDS, B-frags from LDS, 16 MFMAs ---
        bf16x8 a2[2][2];
        #pragma unroll
        for (int mt = 0; mt < 2; ++mt)
            #pragma unroll
            for (int ks = 0; ks < 2; ++ks)
                a2[mt][ks] = *(const bf16x8*)&hb[(mt * 16 + l15) * HSTR + ks * 32 + quad * 8];
        f32x4 acc2[2][4];
        #pragma unroll
        for (int nt = 0; nt < 4; ++nt) {
            const bf16x8 b0 = *(const bf16x8*)&wb2[((nt * 2 + 0) * 64 + l) * 8];
            const bf16x8 b1 = *(const bf16x8*)&wb2[((nt * 2 + 1) * 64 + l) * 8];
            #pragma unroll
            for (int mt = 0; mt < 2; ++mt) {
                f32x4 a = __builtin_amdgcn_mfma_f32_16x16x32_bf16(a2[mt][0], b0, zero4, 0, 0, 0);
                acc2[mt][nt] = __builtin_amdgcn_mfma_f32_16x16x32_bf16(a2[mt][1], b1, a, 0, 0, 0);
            }
        }

        // --- epilogue 2: bn2+relu, attention softmax (shift-invariant), pool ---
        float res[4];
        {
            float sp[4], mk[4];
            #pragma unroll
            for (int nt = 0; nt < 4; ++nt) {
                sp[nt] = 0.f; mk[nt] = 0.f;
                #pragma unroll
                for (int mt = 0; mt < 2; ++mt)
                    #pragma unroll
                    for (int r = 0; r < 4; ++r) {
                        const float h2 = fmaxf(ps2[nt] * acc2[mt][nt][r] + pb2[nt], 0.f);
                        sp[nt] += h2 * wat[mt][r];
                        mk[nt] = fmaxf(mk[nt], h2);
                    }
                sp[nt] += __shfl_xor(sp[nt], 16);
                sp[nt] += __shfl_xor(sp[nt], 32);
                mk[nt] = fmaxf(mk[nt], __shfl_xor(mk[nt], 16));
                mk[nt] = fmaxf(mk[nt], __shfl_xor(mk[nt], 32));
            }
            float e[4], s = 0.f;
            #pragma unroll
            for (int nt = 0; nt < 4; ++nt) { e[nt] = __expf(sp[nt] + battv); s += e[nt]; }
            #pragma unroll
            for (int o = 1; o < 16; o <<= 1) s += __shfl_xor(s, o);
            const float inv = 1.f / s;
            #pragma unroll
            for (int nt = 0; nt < 4; ++nt)
                res[nt] = e[nt] * inv * mk[nt] + resid[nt];
        }
        if (quad == 0) {
            u32x2 rv = { pkbf(res[0], res[1]), pkbf(res[2], res[3]) };
            *(u32x2*)&resstage[(w * PPW + i) * RSTR + c4] = rv;
        }

        // --- rotate pipeline registers (compile-time guarded; SSA-renamed) ---
        if (i + 1 < PPW) {
            #pragma unroll
            for (int mt = 0; mt < 2; ++mt) {
                #pragma unroll
                for (int r = 0; r < 4; ++r) f4c[mt][r] = f4n[mt][r];
                ageoc[mt] = ageon[mt];
            }
            if (i + 2 < PPW) { giN[0] = giN2[0]; giN[1] = giN2[1]; }
        }
    }

    __syncthreads();

    // ---------- phase D: batched out-matmul + LayerNorm + relu ----------
    const f32x4 lngv  = *(const f32x4*)(lng + c4);
    const f32x4 lnbv  = *(const f32x4*)(lnb + c4);
    const f32x4 boutv = *(const f32x4*)(bout + c4);
    bf16x8 a3[2];
    #pragma unroll
    for (int ks = 0; ks < 2; ++ks)
        a3[ks] = *(const bf16x8*)&resstage[l15 * RSTR + ks * 32 + quad * 8];
    f32x4 acc3[4];
    #pragma unroll
    for (int nt = 0; nt < 4; ++nt) {
        const bf16x8 b0 = *(const bf16x8*)&wb3[((nt * 2 + 0) * 64 + l) * 8];
        const bf16x8 b1 = *(const bf16x8*)&wb3[((nt * 2 + 1) * 64 + l) * 8];
        f32x4 a = __builtin_amdgcn_mfma_f32_16x16x32_bf16(a3[0], b0, zero4, 0, 0, 0);
        acc3[nt] = __builtin_amdgcn_mfma_f32_16x16x32_bf16(a3[1], b1, a, 0, 0, 0);
    }
    float y[4], s = 0.f;
    #pragma unroll
    for (int nt = 0; nt < 4; ++nt) { y[nt] = acc3[nt][w] + boutv[nt]; s += y[nt]; }
    #pragma unroll
    for (int o = 1; o < 16; o <<= 1) s += __shfl_xor(s, o);
    const float mu = s * (1.f / 64.f);
    float dv[4], v2 = 0.f;
    #pragma unroll
    for (int nt = 0; nt < 4; ++nt) { dv[nt] = y[nt] - mu; v2 += dv[nt] * dv[nt]; }
    #pragma unroll
    for (int o = 1; o < 16; o <<= 1) v2 += __shfl_xor(v2, o);
    const float rs = rsqrtf(v2 * (1.f / 64.f) + EPSF);
    const int pto = blk * PPB + quad * 4 + w;   // swizzle-corrected output index
    f32x4 ov;
    #pragma unroll
    for (int nt = 0; nt < 4; ++nt)
        ov[nt] = fmaxf(lngv[nt] * dv[nt] * rs + lnbv[nt], 0.f);
    *(f32x4*)(out + (size_t)pto * 64 + c4) = ov;
}

extern "C" void kernel_launch(void* const* d_in, const int* in_sizes, int n_in,
                              void* d_out, int out_size, void* d_ws, size_t ws_size,
                              hipStream_t stream) {
    const float* points   = (const float*)d_in[0];
    const float* features = (const float*)d_in[1];
    const int*   gidxp    = (const int*)d_in[2];
    const bool   pad      = (ws_size >= PP_BYTES);
    float* pp = (float*)d_ws;
    if (pad) {
        hipLaunchKernelGGL(prep_points, dim3((B_ * N_ + 255) / 256), dim3(256), 0, stream,
                           points, pp);
        hipLaunchKernelGGL((bridgenet8<true>), dim3((B_ * N_) / PPB), dim3(256), 0, stream,
            points, pp, features, gidxp,
            (const float*)d_in[3],  (const float*)d_in[4],
            (const float*)d_in[5],  (const float*)d_in[6],  (const float*)d_in[7],  (const float*)d_in[8],
            (const float*)d_in[9],  (const float*)d_in[10],
            (const float*)d_in[11], (const float*)d_in[12], (const float*)d_in[13], (const float*)d_in[14],
            (const float*)d_in[15], (const float*)d_in[16],
            (const float*)d_in[17], (const float*)d_in[18],
            (const float*)d_in[19], (const float*)d_in[20],
            (float*)d_out);
    } else {
        hipLaunchKernelGGL((bridgenet8<false>), dim3((B_ * N_) / PPB), dim3(256), 0, stream,
            points, pp, features, gidxp,
            (const float*)d_in[3],  (const float*)d_in[4],
            (const float*)d_in[5],  (const float*)d_in[6],  (const float*)d_in[7],  (const float*)d_in[8],
            (const float*)d_in[9],  (const float*)d_in[10],
            (const float*)d_in[11], (const float*)d_in[12], (const float*)d_in[13], (const float*)d_in[14],
            (const float*)d_in[15], (const float*)d_in[16],
            (const float*)d_in[17], (const float*)d_in[18],
            (const float*)d_in[19], (const float*)d_in[20],
            (float*)d_out);
    }
}